// Round 1
// baseline (762.935 us; speedup 1.0000x reference)
//
#include <hip/hip_runtime.h>

// FeCAM scoring: scores[b,c] = -diff[c,b,:] @ Minv[c] @ diff[c,b,:]^T
// diff[c,b,e] = (x[b,e] - mean[c,e]) / diag[c,e];  B=32, C=256, D=768.
// Memory-bound: Minv = 604 MB fp32 read exactly once -> ~96 us floor at 6.3 TB/s.
//
// v2: the old per-lane VGPR prefetch held only 128 B/wave in flight
// (Little's law: 2 KB/CU / 900cyc = 2.3 B/cyc = 1.4 TB/s — matched the
// measured ~380 us). This version streams M via global_load_lds (VGPR-free,
// 1 KB/instruction) into wave-private double-buffered LDS stages with
// counted vmcnt(4) waits and NO main-loop barriers -> MLP limited only by
// the vmem queue, HBM-saturating.
//
// Grid = 256 blocks (one class each, 1 block/CU, single round).
// Block = 512 threads (8 waves); wave w owns rows chunk*256 + w*32 .. +32.
// LDS: diff bf16 [32][776] (49.7 KB) + mstage [8 waves][2 bufs][32x32 f32]
// (64 KB) + dist (128 B) = ~113 KB -> 1 block/CU.
//
// global_load_lds writes linearly (base + lane*16); the A-frag ds_read
// (16 lanes, same col-range, 128 B row stride) would be 16-way bank
// conflicted, so the 16B col-chunk is XOR-swizzled with (row&7) on the
// GLOBAL source address (rule #21: both-sides-or-neither) and inverse-
// swizzled on the ds_read side -> 2-way alias (free per m136).

#define BATCH 32
#define NCLS 256
#define DIM 768
#define CHUNK 256              // M rows per chunk (8 waves * 32)
#define NCHUNK (DIM / CHUNK)   // 3
#define NTHREADS 512
#define NWAVE 8
#define PADW (DIM + 8)         // 776 shorts; 388 words %32 = 4 -> 2-way alias (free)

typedef __attribute__((ext_vector_type(8))) short bf16x8;
typedef __attribute__((ext_vector_type(4))) float f32x4;

__device__ __forceinline__ unsigned short f2bf(float f) {
    union { float f; unsigned u; } v; v.f = f;
    unsigned r = v.u + 0x7FFF + ((v.u >> 16) & 1);   // round-nearest-even
    return (unsigned short)(r >> 16);
}
__device__ __forceinline__ float bf2f(unsigned short u) {
    union { unsigned u; float f; } v; v.u = ((unsigned)u) << 16;
    return v.f;
}
__device__ __forceinline__ void cvt8(const f32x4& a, const f32x4& b, bf16x8& o) {
    o[0] = (short)f2bf(a[0]); o[1] = (short)f2bf(a[1]);
    o[2] = (short)f2bf(a[2]); o[3] = (short)f2bf(a[3]);
    o[4] = (short)f2bf(b[0]); o[5] = (short)f2bf(b[1]);
    o[6] = (short)f2bf(b[2]); o[7] = (short)f2bf(b[3]);
}

// async global->LDS, 16 B per lane (lane i lands at l + i*16 bytes)
__device__ __forceinline__ void gload16(const float* g, float* l) {
    __builtin_amdgcn_global_load_lds(
        (const __attribute__((address_space(1))) void*)g,
        (__attribute__((address_space(3))) void*)l,
        16, 0, 0);
}

// Stage 32 rows x 32 cols fp32 (4 KB) = 4 instructions; instruction j covers
// rows j*8 + (lane>>3), source col pre-swizzled so LDS stays linear.
#define STAGE(LB, GP)                          \
    do {                                       \
        gload16((GP),            (LB));        \
        gload16((GP) +  8 * DIM, (LB) + 256);  \
        gload16((GP) + 16 * DIM, (LB) + 512);  \
        gload16((GP) + 24 * DIM, (LB) + 768);  \
    } while (0)

__global__ __launch_bounds__(NTHREADS, 2) void fecam_kernel(
    const float* __restrict__ x,      // [32, 768]
    const float* __restrict__ means,  // [256, 768]
    const float* __restrict__ diags,  // [256, 768]
    const float* __restrict__ Minv,   // [256, 768, 768]
    float* __restrict__ out)          // [32, 256]
{
    __shared__ unsigned short diff[BATCH][PADW];   // bf16 diff, 49.7 KB
    __shared__ float mstage[NWAVE][2][1024];       // 64 KB, wave-private dbuf
    __shared__ float dist[BATCH];

    const int c    = blockIdx.x;    // class
    const int tid  = threadIdx.x;   // 0..511
    const int wave = tid >> 6;
    const int lane = tid & 63;
    const int l15  = lane & 15;
    const int quad = lane >> 4;

    if (tid < BATCH) dist[tid] = 0.f;

    // staging lane geometry: row-in-group + XOR-swizzled 16B col chunk
    const int srow = lane >> 3;                   // 0..7
    const int scol = ((lane & 7) ^ srow) << 2;    // float col of this lane's 16B
    const float* Mc = Minv + (size_t)c * DIM * DIM;
    float* lb0 = &mstage[wave][0][0];
    float* lb1 = &mstage[wave][1][0];

    // pre-stage chunk 0 so its HBM latency hides under the diff prologue
    {
        const float* g0 = Mc + (size_t)(wave * 32 + srow) * DIM + scol;
        STAGE(lb0, g0);
        STAGE(lb1, g0 + 32);
    }

    // ---- diff[b][e] = (x[b,e] - mean[c,e]) / diag[c,e]  (bf16 in LDS) ----
    for (int e = tid; e < DIM; e += NTHREADS) {
        float mv  = means[c * DIM + e];
        float rdv = 1.0f / diags[c * DIM + e];
        #pragma unroll 8
        for (int b = 0; b < BATCH; ++b)
            diff[b][e] = f2bf((x[b * DIM + e] - mv) * rdv);
    }
    __syncthreads();   // drains vmcnt too; pre-staged loads are long retired

    for (int chunk = 0; chunk < NCHUNK; ++chunk) {
        const int d0 = chunk * CHUNK + wave * 32;
        const float* grow = Mc + (size_t)(d0 + srow) * DIM + scol;
        if (chunk != 0) {            // chunk 0 was pre-staged
            STAGE(lb0, grow);
            STAGE(lb1, grow + 32);
        }

        f32x4 acc00 = {0.f,0.f,0.f,0.f};   // rows[0:16)  x batch[0:16)
        f32x4 acc01 = {0.f,0.f,0.f,0.f};   // rows[0:16)  x batch[16:32)
        f32x4 acc10 = {0.f,0.f,0.f,0.f};   // rows[16:32) x batch[0:16)
        f32x4 acc11 = {0.f,0.f,0.f,0.f};   // rows[16:32) x batch[16:32)

        // invariant at top of iter kb: outstanding = [S_kb(4), S_kb+32(4)]
        #pragma unroll
        for (int kb = 0; kb < DIM; kb += 32) {
            float* cb = ((kb >> 5) & 1) ? lb1 : lb0;
            if (kb == DIM - 32) {
                asm volatile("s_waitcnt vmcnt(0)" ::: "memory");  // last stage
            } else {
                asm volatile("s_waitcnt vmcnt(4)" ::: "memory");  // S_kb done, next flying
            }

            // A-frags fp32 from LDS (inverse swizzle on the 16B chunk index)
            const float* r0 = cb + l15 * 32;
            const float* r1 = cb + (16 + l15) * 32;
            const int c0 = ((((quad << 1)    ) ^ (l15 & 7)) << 2);
            const int c1 = ((((quad << 1) | 1) ^ (l15 & 7)) << 2);
            f32x4 a00 = *(const f32x4*)(r0 + c0);
            f32x4 a01 = *(const f32x4*)(r0 + c1);
            f32x4 a10 = *(const f32x4*)(r1 + c0);
            f32x4 a11 = *(const f32x4*)(r1 + c1);
            asm volatile("s_waitcnt lgkmcnt(0)" ::: "memory");  // reads done before overwrite
            if (kb + 64 < DIM) STAGE(cb, grow + kb + 64);       // refill this buffer

            bf16x8 a0, a1;
            cvt8(a00, a01, a0);
            cvt8(a10, a11, a1);
            // B-frag: B[k=quad*8+j][n=lane&15] = diff[n][kb+quad*8+j]
            bf16x8 b0 = *(const bf16x8*)&diff[l15][kb + quad * 8];
            bf16x8 b1 = *(const bf16x8*)&diff[16 + l15][kb + quad * 8];
            acc00 = __builtin_amdgcn_mfma_f32_16x16x32_bf16(a0, b0, acc00, 0,0,0);
            acc01 = __builtin_amdgcn_mfma_f32_16x16x32_bf16(a0, b1, acc01, 0,0,0);
            acc10 = __builtin_amdgcn_mfma_f32_16x16x32_bf16(a1, b0, acc10, 0,0,0);
            acc11 = __builtin_amdgcn_mfma_f32_16x16x32_bf16(a1, b1, acc11, 0,0,0);
        }

        // ---- epilogue: dist[b] += sum_d diff[b,d] * v[d,b] ----
        // C/D layout: col(n=b) = lane&15, row(m) = quad*4 + reg
        float s0 = 0.f, s1 = 0.f;
        #pragma unroll
        for (int r = 0; r < 4; ++r) {
            const int dA = d0 + quad * 4 + r;
            const int dB = dA + 16;
            s0 += acc00[r] * bf2f(diff[l15][dA]);
            s0 += acc10[r] * bf2f(diff[l15][dB]);
            s1 += acc01[r] * bf2f(diff[16 + l15][dA]);
            s1 += acc11[r] * bf2f(diff[16 + l15][dB]);
        }
        s0 += __shfl_xor(s0, 16); s0 += __shfl_xor(s0, 32);
        s1 += __shfl_xor(s1, 16); s1 += __shfl_xor(s1, 32);
        if (lane < 16) {
            atomicAdd(&dist[l15], s0);
            atomicAdd(&dist[16 + l15], s1);
        }
    }

    __syncthreads();
    if (tid < BATCH) out[tid * NCLS + c] = -dist[tid];
}

extern "C" void kernel_launch(void* const* d_in, const int* in_sizes, int n_in,
                              void* d_out, int out_size, void* d_ws, size_t ws_size,
                              hipStream_t stream) {
    const float* x     = (const float*)d_in[0];   // raw_features [32,768]
    const float* means = (const float*)d_in[1];   // class_means  [256,768]
    const float* diags = (const float*)d_in[2];   // class_diags  [256,768]
    const float* Minv  = (const float*)d_in[3];   // class_cov_invs [256,768,768]
    float* out = (float*)d_out;                   // [32,256] fp32

    // every out element is written directly (one block per class) -> no memset
    dim3 grid(NCLS);
    fecam_kernel<<<grid, NTHREADS, 0, stream>>>(x, means, diags, Minv, out);
}